// Round 1
// baseline (22745.268 us; speedup 1.0000x reference)
//
#include <hip/hip_runtime.h>

#define B_   256
#define T_   512
#define H_   512
#define C_   10
#define NGRP 8      // batch groups (32 batches each)
#define BPG  32
#define JT   16     // j-outputs per block
#define NJT  32     // blocks per batch group
#define NTHR 256
// W' layout: [kc=128][gj=64][kk=4] floats = 128 KiB exactly -> 1 block/CU.
// Wave ds_read_b128 at (kc*1024 + lane*16) is a contiguous 1024 B line: zero
// redundancy, zero bank conflicts (stride-1 b128).
#define LDS_BYTES (4 * JT * H_ * 4)

// numpy-SIMD-style (cephes/avx_mathfun) f32 exp — r9-flagged V2 model. DO NOT TOUCH.
__device__ __forceinline__ float expf_cephes(float x) {
    x = fminf(x, 88.3762626647949f);
    x = fmaxf(x, -88.3762626647949f);
    float fx = __fmaf_rn(x, 1.44269504088896341f, 0.5f);
    fx = floorf(fx);
    x = __fmaf_rn(fx, -0.693359375f, x);
    x = __fmaf_rn(fx, 2.12194440e-4f, x);
    float z = __fmul_rn(x, x);
    float y = 1.9875691500E-4f;
    y = __fmaf_rn(y, x, 1.3981999507E-3f);
    y = __fmaf_rn(y, x, 8.3334519073E-3f);
    y = __fmaf_rn(y, x, 4.1665795894E-2f);
    y = __fmaf_rn(y, x, 1.6666665459E-1f);
    y = __fmaf_rn(y, x, 5.0000001201E-1f);
    y = __fmaf_rn(y, z, x);
    y = __fadd_rn(y, 1.0f);
    return ldexpf(y, (int)fx);
}

__device__ __forceinline__ float sig_np(float pre) {
    float e = expf_cephes(-pre);
    return __fdiv_rn(1.0f, __fadd_rn(1.0f, e));
}

// k-ascending 4-FMA chain segment — same op/operand order as r12/r14/r17 FMA8,
// so every (b,j,gate) accumulator is bit-identical to the proven kernel.
#define FMA4(acc, h4, w4)                                                       \
    acc = __fmaf_rn((h4).x, (w4).x, acc); acc = __fmaf_rn((h4).y, (w4).y, acc); \
    acc = __fmaf_rn((h4).z, (w4).z, acc); acc = __fmaf_rn((h4).w, (w4).w, acc);

// one chunk = 4 k values; 8 independent batch chains (ILP=8)
#define STEPF(s)                                                                \
    FMA4(a0, Ha##s, W##s) FMA4(a1, Hb##s, W##s) FMA4(a2, Hc##s, W##s)           \
    FMA4(a3, Hd##s, W##s) FMA4(a4, He##s, W##s) FMA4(a5, Hf##s, W##s)           \
    FMA4(a6, Hg##s, W##s) FMA4(a7, Hh##s, W##s)

// static-slot refill (NO dynamic register indexing — r15 lesson):
// 1 contiguous LDS b128 (weights for this lane's (gate,j), 4 k) +
// 8 wave-uniform global b128 (h[b][4k..4k+3] broadcast — one 16B L2 req each)
#define LOADS(s, n)                                                             \
    W##s  = wr[((n) << 6) + l];                                                 \
    Ha##s = hr0[n]; Hb##s = hr1[n]; Hc##s = hr2[n]; Hd##s = hr3[n];             \
    He##s = hr4[n]; Hf##s = hr5[n]; Hg##s = hr6[n]; Hh##s = hr7[n];

// Epilogue per batch: gather all 4 gate pre-activations to every lane via
// ds_bpermute (pure data movement — values are the bit-exact per-gate chains),
// then V2 rounding verbatim. All 4 gate-groups compute c/h redundantly
// (identical deterministic ops); group g stores batches {2g, 2g+1}.
#define EPI(bi, av, cv)                                                         \
    {                                                                           \
        const float pre = __fadd_rn(__fadd_rn(__fmul_rn(wx, xt##bi), av), bs);  \
        const int pbits = __float_as_int(pre);                                  \
        const float pg = __int_as_float(__builtin_amdgcn_ds_bpermute(ix0, pbits)); \
        const float pi = __int_as_float(__builtin_amdgcn_ds_bpermute(ix1, pbits)); \
        const float pf = __int_as_float(__builtin_amdgcn_ds_bpermute(ix2, pbits)); \
        const float po = __int_as_float(__builtin_amdgcn_ds_bpermute(ix3, pbits)); \
        const float iv = sig_np(pi);                                            \
        const float fv = sig_np(pf);                                            \
        const float ov = sig_np(po);                                            \
        cv = __fadd_rn(__fmul_rn(pg, iv), __fmul_rn(cv, fv));                   \
        const float hn = __fmul_rn(cv, ov);                                     \
        if (((bi) >> 1) == g) hwp[(bi) * H_] = hn;                              \
    }

__global__ void __launch_bounds__(NTHR, 1) lstm_fast(
    const float* __restrict__ x,
    const float* __restrict__ wgh, const float* __restrict__ wih,
    const float* __restrict__ wfh, const float* __restrict__ woh,
    const float* __restrict__ wgx, const float* __restrict__ wix,
    const float* __restrict__ wfx, const float* __restrict__ wox,
    const float* __restrict__ bgp, const float* __restrict__ bip,
    const float* __restrict__ bfp, const float* __restrict__ bop,
    float* __restrict__ hbuf, unsigned int* __restrict__ cnt)
{
    extern __shared__ float lds[];   // W'[kc][gj][kk]
    const int tid = threadIdx.x;
    const int bg  = blockIdx.x & (NGRP - 1);
    const int jt  = blockIdx.x >> 3;
    const int j0  = jt * JT;

    // stage: lds[(k>>2)*256 + (g*16+jj)*4 + (k&3)] = W_g[k][j0+jj]  (exact f32 bits)
    // global reads: 16 consecutive j per 16 lanes (64B segments); LDS writes 2-way max.
    const float* wh[4] = {wgh, wih, wfh, woh};
    for (int g2 = 0; g2 < 4; ++g2) {
        const float* w = wh[g2];
        for (int idx = tid; idx < H_ * JT; idx += NTHR) {
            const int k   = idx >> 4;
            const int jj2 = idx & (JT - 1);
            lds[((k >> 2) << 8) + (((g2 << 4) + jj2) << 2) + (k & 3)] =
                w[k * H_ + j0 + jj2];
        }
    }
    __syncthreads();

    // lane mapping: l = (gate g, column jj); wave wv owns 8 batches in registers.
    const int l   = tid & 63;
    const int wv  = tid >> 6;
    const int g   = l >> 4;
    const int jj  = l & 15;
    const int jg  = j0 + jj;
    const int b0w = bg * BPG + wv * 8;

    const float* wxs = (g == 0) ? wgx : (g == 1) ? wix : (g == 2) ? wfx : wox;
    const float* bss = (g == 0) ? bgp : (g == 1) ? bip : (g == 2) ? bfp : bop;
    const float wx = wxs[jg];
    const float bs = bss[jg];

    // bpermute byte-indices: gate-0..3 lanes holding this jj
    const int ix0 = (jj + 0)  << 2;
    const int ix1 = (jj + 16) << 2;
    const int ix2 = (jj + 32) << 2;
    const int ix3 = (jj + 48) << 2;

    const float4* wr = (const float4*)lds;

    float c0 = 0.f, c1 = 0.f, c2 = 0.f, c3 = 0.f;
    float c4 = 0.f, c5 = 0.f, c6 = 0.f, c7 = 0.f;

    for (int t = 0; t < T_; ++t) {
        if (t > 0) {
            if (tid == 0) {
                while (__hip_atomic_load(&cnt[t * NGRP + bg], __ATOMIC_RELAXED,
                                         __HIP_MEMORY_SCOPE_AGENT) < NJT) {
                    __builtin_amdgcn_s_sleep(1);
                }
                (void)__hip_atomic_load(&cnt[t * NGRP + bg], __ATOMIC_ACQUIRE,
                                        __HIP_MEMORY_SCOPE_AGENT);
            }
            __syncthreads();
        }

        const float xt0 = x[(b0w + 0) * T_ + t];
        const float xt1 = x[(b0w + 1) * T_ + t];
        const float xt2 = x[(b0w + 2) * T_ + t];
        const float xt3 = x[(b0w + 3) * T_ + t];
        const float xt4 = x[(b0w + 4) * T_ + t];
        const float xt5 = x[(b0w + 5) * T_ + t];
        const float xt6 = x[(b0w + 6) * T_ + t];
        const float xt7 = x[(b0w + 7) * T_ + t];

        const float* hb = hbuf + (size_t)(t & 1) * B_ * H_;
        const float4* hr0 = (const float4*)(hb + (b0w + 0) * H_);
        const float4* hr1 = (const float4*)(hb + (b0w + 1) * H_);
        const float4* hr2 = (const float4*)(hb + (b0w + 2) * H_);
        const float4* hr3 = (const float4*)(hb + (b0w + 3) * H_);
        const float4* hr4 = (const float4*)(hb + (b0w + 4) * H_);
        const float4* hr5 = (const float4*)(hb + (b0w + 5) * H_);
        const float4* hr6 = (const float4*)(hb + (b0w + 6) * H_);
        const float4* hr7 = (const float4*)(hb + (b0w + 7) * H_);

        float a0 = 0.f, a1 = 0.f, a2 = 0.f, a3 = 0.f;
        float a4 = 0.f, a5 = 0.f, a6 = 0.f, a7 = 0.f;

        // 4-slot STATIC software pipeline (r17-proven skeleton): slot s consumed
        // then refilled with chunk n+4 -> loads issued ~4 chunks (~300 cyc) early.
        // Chunks consumed strictly ascending -> bit-identical chains.
        float4 W0, W1, W2, W3;
        float4 Ha0, Hb0, Hc0, Hd0, He0, Hf0, Hg0, Hh0;
        float4 Ha1, Hb1, Hc1, Hd1, He1, Hf1, Hg1, Hh1;
        float4 Ha2, Hb2, Hc2, Hd2, He2, Hf2, Hg2, Hh2;
        float4 Ha3, Hb3, Hc3, Hd3, He3, Hf3, Hg3, Hh3;

        LOADS(0, 0) LOADS(1, 1) LOADS(2, 2) LOADS(3, 3)

        #pragma unroll 1
        for (int m = 0; m < 31; ++m) {
            const int n = 4 * m;
            STEPF(0) LOADS(0, n + 4)
            STEPF(1) LOADS(1, n + 5)
            STEPF(2) LOADS(2, n + 6)
            STEPF(3) LOADS(3, n + 7)
        }
        STEPF(0) STEPF(1) STEPF(2) STEPF(3)   // chunks 124..127

        float* hw  = hbuf + (size_t)((t + 1) & 1) * B_ * H_;
        float* hwp = hw + b0w * H_ + jg;

        EPI(0, a0, c0) EPI(1, a1, c1) EPI(2, a2, c2) EPI(3, a3, c3)
        EPI(4, a4, c4) EPI(5, a5, c5) EPI(6, a6, c6) EPI(7, a7, c7)

        __syncthreads();   // s_waitcnt vmcnt(0) before s_barrier: h stores drained
        if (tid == 0) {
            // RELEASE fetch_add alone provides the store->flag release fence.
            __hip_atomic_fetch_add(&cnt[(t + 1) * NGRP + bg], 1u,
                                   __ATOMIC_RELEASE, __HIP_MEMORY_SCOPE_AGENT);
        }
    }
}

// out[b][c] = dot_seq(h_T[b], wph[c]) + bp[c]  — bit-identical chain to r12's proj
__global__ void __launch_bounds__(64) proj_kernel(
    const float* __restrict__ hbuf, const float* __restrict__ wph,
    const float* __restrict__ bp, float* __restrict__ out)
{
    const int b = blockIdx.x, tid = threadIdx.x;
    const float* h = hbuf + (size_t)b * H_;   // final h in buffer 0 (T even)
    if (tid < C_) {
        float acc = 0.f;
        for (int k = 0; k < H_; ++k)
            acc = __fmaf_rn(h[k], wph[tid * H_ + k], acc);
        out[b * C_ + tid] = __fadd_rn(acc, bp[tid]);
    }
}

extern "C" void kernel_launch(void* const* d_in, const int* in_sizes, int n_in,
                              void* d_out, int out_size, void* d_ws, size_t ws_size,
                              hipStream_t stream)
{
    const float* x   = (const float*)d_in[0];
    const float* wgx = (const float*)d_in[1];
    const float* wgh = (const float*)d_in[2];
    const float* bgp = (const float*)d_in[3];
    const float* wix = (const float*)d_in[4];
    const float* wih = (const float*)d_in[5];
    const float* bip = (const float*)d_in[6];
    const float* wfx = (const float*)d_in[7];
    const float* wfh = (const float*)d_in[8];
    const float* bfp = (const float*)d_in[9];
    const float* wox = (const float*)d_in[10];
    const float* woh = (const float*)d_in[11];
    const float* bop = (const float*)d_in[12];
    const float* wph = (const float*)d_in[13];
    const float* bp  = (const float*)d_in[14];
    float* out = (float*)d_out;

    float* hbuf = (float*)d_ws;                                   // 2*B*H f32 = 1 MB
    unsigned int* cnt = (unsigned int*)((char*)d_ws + (size_t)2 * B_ * H_ * 4);
    size_t zero_bytes = (size_t)2 * B_ * H_ * 4 + (size_t)(T_ + 1) * NGRP * 4;
    hipMemsetAsync(d_ws, 0, zero_bytes, stream);   // h0 = 0, counters = 0

    hipFuncSetAttribute((const void*)lstm_fast,
                        hipFuncAttributeMaxDynamicSharedMemorySize, LDS_BYTES);

    void* args[] = {&x, &wgh, &wih, &wfh, &woh, &wgx, &wix, &wfx, &wox,
                    &bgp, &bip, &bfp, &bop, &hbuf, &cnt};
    hipLaunchCooperativeKernel((const void*)lstm_fast, dim3(NGRP * NJT), dim3(NTHR),
                               args, LDS_BYTES, stream);

    proj_kernel<<<B_, 64, 0, stream>>>(hbuf, wph, bp, out);
}

// Round 2
// 17922.350 us; speedup vs baseline: 1.2691x; 1.2691x over previous
//
#include <hip/hip_runtime.h>

#define B_   256
#define T_   512
#define H_   512
#define C_   10
#define NGRP 8      // batch groups (32 batches each)
#define BPG  32
#define JT   16     // j-outputs per block
#define NJT  32     // blocks per batch group
#define NTHR 512    // 8 waves x 4 batches/wave: slot state 80 VGPR -> pipeline FITS
// W' layout: [kc=128][gj=64][kk=4] floats = 128 KiB exactly -> 1 block/CU.
// Wave ds_read_b128 at (kc*1024 + lane*16) is a contiguous 1024 B line: zero
// redundancy, zero bank conflicts (stride-1 b128).
#define LDS_BYTES (4 * JT * H_ * 4)

// numpy-SIMD-style (cephes/avx_mathfun) f32 exp — r9-flagged V2 model. DO NOT TOUCH.
__device__ __forceinline__ float expf_cephes(float x) {
    x = fminf(x, 88.3762626647949f);
    x = fmaxf(x, -88.3762626647949f);
    float fx = __fmaf_rn(x, 1.44269504088896341f, 0.5f);
    fx = floorf(fx);
    x = __fmaf_rn(fx, -0.693359375f, x);
    x = __fmaf_rn(fx, 2.12194440e-4f, x);
    float z = __fmul_rn(x, x);
    float y = 1.9875691500E-4f;
    y = __fmaf_rn(y, x, 1.3981999507E-3f);
    y = __fmaf_rn(y, x, 8.3334519073E-3f);
    y = __fmaf_rn(y, x, 4.1665795894E-2f);
    y = __fmaf_rn(y, x, 1.6666665459E-1f);
    y = __fmaf_rn(y, x, 5.0000001201E-1f);
    y = __fmaf_rn(y, z, x);
    y = __fadd_rn(y, 1.0f);
    return ldexpf(y, (int)fx);
}

__device__ __forceinline__ float sig_np(float pre) {
    float e = expf_cephes(-pre);
    return __fdiv_rn(1.0f, __fadd_rn(1.0f, e));
}

// k-ascending 4-FMA chain segment — same op/operand order as r12/r14/r17 FMA8,
// so every (b,j,gate) accumulator is bit-identical to the proven kernel.
#define FMA4(acc, h4, w4)                                                       \
    acc = __fmaf_rn((h4).x, (w4).x, acc); acc = __fmaf_rn((h4).y, (w4).y, acc); \
    acc = __fmaf_rn((h4).z, (w4).z, acc); acc = __fmaf_rn((h4).w, (w4).w, acc);

// one chunk = 4 k values; 4 independent batch chains (ILP=4, x2 waves/SIMD TLP)
#define STEPF(s)                                                                \
    FMA4(a0, Ha##s, W##s) FMA4(a1, Hb##s, W##s)                                 \
    FMA4(a2, Hc##s, W##s) FMA4(a3, Hd##s, W##s)

// static-slot refill (NO dynamic register indexing — r15 lesson):
// 1 contiguous LDS b128 (weights for this lane's (gate,j), 4 k) +
// 4 wave-uniform global b128 (h[b][4k..4k+3] broadcast — one 16B L2 req each).
// Slot footprint: 5 float4 = 20 VGPR; depth 4 -> 80 VGPR live, fits (r0 held 96).
#define LOADS(s, n)                                                             \
    W##s  = wr[((n) << 6) + l];                                                 \
    Ha##s = hr0[n]; Hb##s = hr1[n]; Hc##s = hr2[n]; Hd##s = hr3[n];

// Epilogue per batch: gather all 4 gate pre-activations to every lane via
// ds_bpermute (pure data movement — values are the bit-exact per-gate chains),
// then V2 rounding verbatim. All 4 gate-groups compute c/h redundantly
// (identical deterministic ops); gate-group g stores batch bi==g.
#define EPI(bi, av, cv)                                                         \
    {                                                                           \
        const float pre = __fadd_rn(__fadd_rn(__fmul_rn(wx, xt##bi), av), bs);  \
        const int pbits = __float_as_int(pre);                                  \
        const float pg = __int_as_float(__builtin_amdgcn_ds_bpermute(ix0, pbits)); \
        const float pi = __int_as_float(__builtin_amdgcn_ds_bpermute(ix1, pbits)); \
        const float pf = __int_as_float(__builtin_amdgcn_ds_bpermute(ix2, pbits)); \
        const float po = __int_as_float(__builtin_amdgcn_ds_bpermute(ix3, pbits)); \
        const float iv = sig_np(pi);                                            \
        const float fv = sig_np(pf);                                            \
        const float ov = sig_np(po);                                            \
        cv = __fadd_rn(__fmul_rn(pg, iv), __fmul_rn(cv, fv));                   \
        const float hn = __fmul_rn(cv, ov);                                     \
        if ((bi) == g) hwp[(bi) * H_] = hn;                                     \
    }

__global__ void __launch_bounds__(NTHR, 1) lstm_fast(
    const float* __restrict__ x,
    const float* __restrict__ wgh, const float* __restrict__ wih,
    const float* __restrict__ wfh, const float* __restrict__ woh,
    const float* __restrict__ wgx, const float* __restrict__ wix,
    const float* __restrict__ wfx, const float* __restrict__ wox,
    const float* __restrict__ bgp, const float* __restrict__ bip,
    const float* __restrict__ bfp, const float* __restrict__ bop,
    float* __restrict__ hbuf, unsigned int* __restrict__ cnt)
{
    extern __shared__ float lds[];   // W'[kc][gj][kk]
    const int tid = threadIdx.x;
    const int bg  = blockIdx.x & (NGRP - 1);
    const int jt  = blockIdx.x >> 3;
    const int j0  = jt * JT;

    // stage: lds[(k>>2)*256 + (g*16+jj)*4 + (k&3)] = W_g[k][j0+jj]  (exact f32 bits)
    const float* wh[4] = {wgh, wih, wfh, woh};
    for (int g2 = 0; g2 < 4; ++g2) {
        const float* w = wh[g2];
        for (int idx = tid; idx < H_ * JT; idx += NTHR) {
            const int k   = idx >> 4;
            const int jj2 = idx & (JT - 1);
            lds[((k >> 2) << 8) + (((g2 << 4) + jj2) << 2) + (k & 3)] =
                w[k * H_ + j0 + jj2];
        }
    }
    __syncthreads();

    // lane mapping: l = (gate g, column jj); wave wv owns 4 batches in registers.
    const int l   = tid & 63;
    const int wv  = tid >> 6;                 // 0..7
    const int g   = l >> 4;
    const int jj  = l & 15;
    const int jg  = j0 + jj;
    const int b0w = bg * BPG + wv * 4;

    const float* wxs = (g == 0) ? wgx : (g == 1) ? wix : (g == 2) ? wfx : wox;
    const float* bss = (g == 0) ? bgp : (g == 1) ? bip : (g == 2) ? bfp : bop;
    const float wx = wxs[jg];
    const float bs = bss[jg];

    // bpermute byte-indices: gate-0..3 lanes holding this jj
    const int ix0 = (jj + 0)  << 2;
    const int ix1 = (jj + 16) << 2;
    const int ix2 = (jj + 32) << 2;
    const int ix3 = (jj + 48) << 2;

    const float4* wr = (const float4*)lds;

    float c0 = 0.f, c1 = 0.f, c2 = 0.f, c3 = 0.f;

    for (int t = 0; t < T_; ++t) {
        if (t > 0) {
            if (tid == 0) {
                while (__hip_atomic_load(&cnt[t * NGRP + bg], __ATOMIC_RELAXED,
                                         __HIP_MEMORY_SCOPE_AGENT) < NJT) {
                    __builtin_amdgcn_s_sleep(1);
                }
                (void)__hip_atomic_load(&cnt[t * NGRP + bg], __ATOMIC_ACQUIRE,
                                        __HIP_MEMORY_SCOPE_AGENT);
            }
            __syncthreads();
        }

        const float xt0 = x[(b0w + 0) * T_ + t];
        const float xt1 = x[(b0w + 1) * T_ + t];
        const float xt2 = x[(b0w + 2) * T_ + t];
        const float xt3 = x[(b0w + 3) * T_ + t];

        const float* hb = hbuf + (size_t)(t & 1) * B_ * H_;
        const float4* hr0 = (const float4*)(hb + (b0w + 0) * H_);
        const float4* hr1 = (const float4*)(hb + (b0w + 1) * H_);
        const float4* hr2 = (const float4*)(hb + (b0w + 2) * H_);
        const float4* hr3 = (const float4*)(hb + (b0w + 3) * H_);

        float a0 = 0.f, a1 = 0.f, a2 = 0.f, a3 = 0.f;

        // 4-slot STATIC software pipeline (r17-proven skeleton): slot s consumed
        // then refilled with chunk n+4 -> loads issued ~4 chunks (~250 cyc) early.
        // Chunks consumed strictly ascending -> bit-identical chains.
        float4 W0, W1, W2, W3;
        float4 Ha0, Hb0, Hc0, Hd0;
        float4 Ha1, Hb1, Hc1, Hd1;
        float4 Ha2, Hb2, Hc2, Hd2;
        float4 Ha3, Hb3, Hc3, Hd3;

        LOADS(0, 0) LOADS(1, 1) LOADS(2, 2) LOADS(3, 3)

        #pragma unroll 1
        for (int m = 0; m < 31; ++m) {
            const int n = 4 * m;
            STEPF(0) LOADS(0, n + 4)
            STEPF(1) LOADS(1, n + 5)
            STEPF(2) LOADS(2, n + 6)
            STEPF(3) LOADS(3, n + 7)
        }
        STEPF(0) STEPF(1) STEPF(2) STEPF(3)   // chunks 124..127

        float* hw  = hbuf + (size_t)((t + 1) & 1) * B_ * H_;
        float* hwp = hw + b0w * H_ + jg;

        EPI(0, a0, c0) EPI(1, a1, c1) EPI(2, a2, c2) EPI(3, a3, c3)

        __syncthreads();   // s_waitcnt vmcnt(0) before s_barrier: h stores drained
        if (tid == 0) {
            // RELEASE fetch_add alone provides the store->flag release fence.
            __hip_atomic_fetch_add(&cnt[(t + 1) * NGRP + bg], 1u,
                                   __ATOMIC_RELEASE, __HIP_MEMORY_SCOPE_AGENT);
        }
    }
}

// out[b][c] = dot_seq(h_T[b], wph[c]) + bp[c]  — bit-identical chain to r12's proj
__global__ void __launch_bounds__(64) proj_kernel(
    const float* __restrict__ hbuf, const float* __restrict__ wph,
    const float* __restrict__ bp, float* __restrict__ out)
{
    const int b = blockIdx.x, tid = threadIdx.x;
    const float* h = hbuf + (size_t)b * H_;   // final h in buffer 0 (T even)
    if (tid < C_) {
        float acc = 0.f;
        for (int k = 0; k < H_; ++k)
            acc = __fmaf_rn(h[k], wph[tid * H_ + k], acc);
        out[b * C_ + tid] = __fadd_rn(acc, bp[tid]);
    }
}

extern "C" void kernel_launch(void* const* d_in, const int* in_sizes, int n_in,
                              void* d_out, int out_size, void* d_ws, size_t ws_size,
                              hipStream_t stream)
{
    const float* x   = (const float*)d_in[0];
    const float* wgx = (const float*)d_in[1];
    const float* wgh = (const float*)d_in[2];
    const float* bgp = (const float*)d_in[3];
    const float* wix = (const float*)d_in[4];
    const float* wih = (const float*)d_in[5];
    const float* bip = (const float*)d_in[6];
    const float* wfx = (const float*)d_in[7];
    const float* wfh = (const float*)d_in[8];
    const float* bfp = (const float*)d_in[9];
    const float* wox = (const float*)d_in[10];
    const float* woh = (const float*)d_in[11];
    const float* bop = (const float*)d_in[12];
    const float* wph = (const float*)d_in[13];
    const float* bp  = (const float*)d_in[14];
    float* out = (float*)d_out;

    float* hbuf = (float*)d_ws;                                   // 2*B*H f32 = 1 MB
    unsigned int* cnt = (unsigned int*)((char*)d_ws + (size_t)2 * B_ * H_ * 4);
    size_t zero_bytes = (size_t)2 * B_ * H_ * 4 + (size_t)(T_ + 1) * NGRP * 4;
    hipMemsetAsync(d_ws, 0, zero_bytes, stream);   // h0 = 0, counters = 0

    hipFuncSetAttribute((const void*)lstm_fast,
                        hipFuncAttributeMaxDynamicSharedMemorySize, LDS_BYTES);

    void* args[] = {&x, &wgh, &wih, &wfh, &woh, &wgx, &wix, &wfx, &wox,
                    &bgp, &bip, &bfp, &bop, &hbuf, &cnt};
    hipLaunchCooperativeKernel((const void*)lstm_fast, dim3(NGRP * NJT), dim3(NTHR),
                               args, LDS_BYTES, stream);

    proj_kernel<<<B_, 64, 0, stream>>>(hbuf, wph, bp, out);
}